// Round 16
// baseline (92.498 us; speedup 1.0000x reference)
//
#include <hip/hip_runtime.h>
#include <hip/hip_bf16.h>
#include <stdint.h>

// SelfBallPointQuery: B=16, C=3, N=2048, RADIUS^2=0.04, MAX_SAMPLES=64.
// R16: INSTRUMENTATION ROUND. R13/R14/R15 structural changes were all ~neutral
// and the kernel has been invisible in rocprof (below the 40us fill-op top-5
// cutoff) since R12 -- four blind rounds. This round runs the proven R14 body
// TWICE per launch (identical recompute+rewrite: deterministic, correct) so
// the dispatch exceeds 40us and returns with full counters (VALUBusy, FETCH
// spill check, LDS conflicts, occupancy). Also bounds (512,4) instead of
// (512,8): same residency (grid 512 = 2 blocks/CU) but removes the VGPR-64
// clamp as a hidden spill variable.

#define B_DIM 16
#define N_PTS 2048
#define K_OUT 64
#define R2 0.04f
#define WAVES 8
#define BLOCK_T (WAVES * 64)            // 512
#define JPW (N_PTS / WAVES)             // 256 points per wave
#define WPW (JPW / 32)                  // 8 mask words per lane
#define ROWPAD 65                       // LDS row stride

typedef float v2f __attribute__((ext_vector_type(2)));

__global__ __launch_bounds__(BLOCK_T, 4) void ball_query_kernel(
    const float* __restrict__ pcs,   // (B, 3, N)
    int* __restrict__ out)           // (B, N, 64) int32
{
#pragma clang fp contract(off)
    __shared__ int rows[64 * ROWPAD];
    __shared__ int cntS[WAVES][64];
    __shared__ int qfS[WAVES][64];

    const int b    = blockIdx.x >> 5;
    const int qg   = blockIdx.x & 31;
    const int tid  = threadIdx.x;
    const int wave = __builtin_amdgcn_readfirstlane(tid >> 6); // uniform
    const int lane = tid & 63;

    const float* __restrict__ sx = pcs + (size_t)b * 3 * N_PTS;
    const float* __restrict__ sy = sx + N_PTS;
    const float* __restrict__ sz = sy + N_PTS;

    const int qi = qg * 64 + lane;
    const float qx = sx[qi];
    const float qy = sy[qi];
    const float qz = sz[qi];
    const v2f qx2 = {qx, qx}, qy2 = {qy, qy}, qz2 = {qz, qz};

    const int jbase = wave * JPW;
    int* const obase = out + (size_t)(b * N_PTS + qg * 64) * K_OUT;

    for (int rep = 0; rep < 2; ++rep) {   // x2 work: identical output, makes
                                          // the dispatch profiler-visible
        // ---- dense test phase: 8 words x 32 bits per lane ----
        unsigned mask[WPW];
        for (int t = 0; t < WPW; ++t) {
            unsigned m = 0;
            #pragma unroll
            for (int k = 30; k >= 0; k -= 2) {   // descending pairs
                const int j = jbase + t * 32 + k;   // uniform, even
                const v2f px = *(const v2f*)(sx + j);   // s_load path
                const v2f py = *(const v2f*)(sy + j);
                const v2f pz = *(const v2f*)(sz + j);
                const v2f dx = px - qx2;
                const v2f dy = py - qy2;
                const v2f dz = pz - qz2;
                const v2f d2 = (dx * dx + dy * dy) + dz * dz;
                m = m + m + (unsigned)(d2.y < R2);
                m = m + m + (unsigned)(d2.x < R2);
            }
            mask[t] = m;
        }

        int cnt = 0;
        #pragma unroll
        for (int t = 0; t < WPW; ++t) cnt += __builtin_popcount(mask[t]);
        int qf = -1;
        #pragma unroll
        for (int t = 0; t < WPW; ++t) {
            if (qf < 0 && mask[t] != 0u)
                qf = jbase + t * 32 + __builtin_ctz(mask[t]);
        }
        cntS[wave][lane] = cnt;
        qfS[wave][lane]  = qf;
        __syncthreads();

        int base = 0, tc = 0, gfirst = 0;
        #pragma unroll
        for (int w = 0; w < WAVES; ++w) {
            const int c = cntS[w][lane];
            const int f = qfS[w][lane];
            if (w < wave) base += c;
            gfirst = (tc == 0 && c > 0) ? f : gfirst;
            tc += c;
        }

        // ---- sparse emit into LDS rows ----
        int slot = base;
        for (int t = 0; t < WPW; ++t) {
            unsigned m = mask[t];
            while (m != 0u && slot < K_OUT) {
                const int k = (int)__builtin_ctz(m);
                rows[lane * ROWPAD + slot] = jbase + t * 32 + k;
                m &= m - 1u;
                ++slot;
            }
        }

        // ---- pad ----
        #pragma unroll
        for (int s0 = 0; s0 < K_OUT / WAVES; ++s0) {
            const int s = wave * (K_OUT / WAVES) + s0;
            if (s >= tc) rows[lane * ROWPAD + s] = gfirst;
        }
        __syncthreads();

        // ---- coalesced copy-out ----
        #pragma unroll
        for (int it = 0; it < (64 * K_OUT) / BLOCK_T; ++it) {
            const int idx = it * BLOCK_T + tid;
            const int r = idx >> 6;
            const int c = idx & 63;
            obase[idx] = rows[r * ROWPAD + c];
        }
        __syncthreads();   // rows/cntS reuse safety for rep 2
    }
}

extern "C" void kernel_launch(void* const* d_in, const int* in_sizes, int n_in,
                              void* d_out, int out_size, void* d_ws, size_t ws_size,
                              hipStream_t stream) {
    const float* pcs = (const float*)d_in[0];
    int* out = (int*)d_out;
    const int grid = B_DIM * 32;     // 512 blocks
    ball_query_kernel<<<grid, BLOCK_T, 0, stream>>>(pcs, out);
}

// Round 17
// 75.390 us; speedup vs baseline: 1.2269x; 1.2269x over previous
//
#include <hip/hip_runtime.h>
#include <hip/hip_bf16.h>
#include <stdint.h>

// SelfBallPointQuery: B=16, C=3, N=2048, RADIUS^2=0.04, MAX_SAMPLES=64.
// R17 = R14 structure (lane=query, SMEM point fetch, LDS-staged emit) with
// the test-phase math forced onto VOP3P packed-fp32 via inline asm.
// R16 instrumentation: 4,000 VALU insts/wave/pass measured == the SCALARIZED
// count; compiler never emitted v_pk ops from ext-vector float2. Forcing:
//   dx = px + (-qx)  as v_pk_add_f32 (point pair from SGPRs, "s" constraint;
//   pre-negated query in VGPRs -- negation exact, squaring kills the sign,
//   rounding identical to numpy's (dx*dx+dy*dy)+dz*dz in RN)
// Per pair-step: 8 pk + 2 cmp + 2 addc = 12 VALU / 2 points.

#define B_DIM 16
#define N_PTS 2048
#define K_OUT 64
#define R2 0.04f
#define WAVES 8
#define BLOCK_T (WAVES * 64)            // 512
#define JPW (N_PTS / WAVES)             // 256 points per wave
#define WPW (JPW / 32)                  // 8 mask words per lane
#define ROWPAD 65                       // LDS row stride

typedef float v2f __attribute__((ext_vector_type(2)));

__global__ __launch_bounds__(BLOCK_T, 4) void ball_query_kernel(
    const float* __restrict__ pcs,   // (B, 3, N)
    int* __restrict__ out)           // (B, N, 64) int32
{
    __shared__ int rows[64 * ROWPAD];
    __shared__ int cntS[WAVES][64];
    __shared__ int qfS[WAVES][64];

    const int b    = blockIdx.x >> 5;
    const int qg   = blockIdx.x & 31;
    const int tid  = threadIdx.x;
    const int wave = __builtin_amdgcn_readfirstlane(tid >> 6); // uniform
    const int lane = tid & 63;

    const float* __restrict__ sx = pcs + (size_t)b * 3 * N_PTS;
    const float* __restrict__ sy = sx + N_PTS;
    const float* __restrict__ sz = sy + N_PTS;

    const int qi = qg * 64 + lane;
    // pre-negated query coords, broadcast into both halves of a VGPR pair
    const float nx = -sx[qi], ny = -sy[qi], nz = -sz[qi];
    const v2f nqx = {nx, nx}, nqy = {ny, ny}, nqz = {nz, nz};

    const int jbase = wave * JPW;
    int* const obase = out + (size_t)(b * N_PTS + qg * 64) * K_OUT;

    // ---- dense test phase: 8 words x 32 bits per lane, 2 points/step ----
    unsigned mask[WPW];
    for (int t = 0; t < WPW; ++t) {
        unsigned m = 0;
        #pragma unroll
        for (int k = 30; k >= 0; k -= 2) {    // descending pairs: bits k+1, k
            const int j = jbase + t * 32 + k; // wave-uniform, even (8B align)
            const v2f px = *(const v2f*)(sx + j);   // uniform -> s_load
            const v2f py = *(const v2f*)(sy + j);
            const v2f pz = *(const v2f*)(sz + j);
            v2f dx, dy, dz, xx, yy, zz, s0, d2;
            asm("v_pk_add_f32 %0, %1, %2" : "=v"(dx) : "s"(px), "v"(nqx));
            asm("v_pk_add_f32 %0, %1, %2" : "=v"(dy) : "s"(py), "v"(nqy));
            asm("v_pk_add_f32 %0, %1, %2" : "=v"(dz) : "s"(pz), "v"(nqz));
            asm("v_pk_mul_f32 %0, %1, %1" : "=v"(xx) : "v"(dx));
            asm("v_pk_mul_f32 %0, %1, %1" : "=v"(yy) : "v"(dy));
            asm("v_pk_mul_f32 %0, %1, %1" : "=v"(zz) : "v"(dz));
            asm("v_pk_add_f32 %0, %1, %2" : "=v"(s0) : "v"(xx), "v"(yy));
            asm("v_pk_add_f32 %0, %1, %2" : "=v"(d2) : "v"(s0), "v"(zz));
            // bit k+1 (point j+1) first, then bit k (point j)
            m = m + m + (unsigned)(d2.y < R2);
            m = m + m + (unsigned)(d2.x < R2);
        }
        mask[t] = m;
    }

    // per-lane count + first hit within this wave's window
    int cnt = 0;
    #pragma unroll
    for (int t = 0; t < WPW; ++t) cnt += __builtin_popcount(mask[t]);
    int qf = -1;
    #pragma unroll
    for (int t = 0; t < WPW; ++t) {
        if (qf < 0 && mask[t] != 0u)
            qf = jbase + t * 32 + __builtin_ctz(mask[t]);
    }
    cntS[wave][lane] = cnt;
    qfS[wave][lane]  = qf;
    __syncthreads();

    // prefix over earlier waves' counts for my query; global first hit
    int base = 0, tc = 0, gfirst = 0;
    #pragma unroll
    for (int w = 0; w < WAVES; ++w) {
        const int c = cntS[w][lane];
        const int f = qfS[w][lane];
        if (w < wave) base += c;
        gfirst = (tc == 0 && c > 0) ? f : gfirst;
        tc += c;
    }

    // ---- sparse emit into LDS rows (disjoint slot ranges across waves) ----
    int slot = base;
    for (int t = 0; t < WPW; ++t) {
        unsigned m = mask[t];
        while (m != 0u && slot < K_OUT) {
            const int k = (int)__builtin_ctz(m);
            rows[lane * ROWPAD + slot] = jbase + t * 32 + k;
            m &= m - 1u;
            ++slot;
        }
    }

    // ---- pad: 8 slots per wave cover [0,64); fill gfirst where s >= tc ----
    #pragma unroll
    for (int s0i = 0; s0i < K_OUT / WAVES; ++s0i) {
        const int s = wave * (K_OUT / WAVES) + s0i;
        if (s >= tc) rows[lane * ROWPAD + s] = gfirst;
    }
    __syncthreads();

    // ---- coalesced copy-out: 64 rows x 64 ints ----
    #pragma unroll
    for (int it = 0; it < (64 * K_OUT) / BLOCK_T; ++it) {
        const int idx = it * BLOCK_T + tid;
        const int r = idx >> 6;
        const int c = idx & 63;
        obase[idx] = rows[r * ROWPAD + c];
    }
}

extern "C" void kernel_launch(void* const* d_in, const int* in_sizes, int n_in,
                              void* d_out, int out_size, void* d_ws, size_t ws_size,
                              hipStream_t stream) {
    const float* pcs = (const float*)d_in[0];
    int* out = (int*)d_out;
    const int grid = B_DIM * 32;     // 512 blocks
    ball_query_kernel<<<grid, BLOCK_T, 0, stream>>>(pcs, out);
}